// Round 1
// baseline (340.304 us; speedup 1.0000x reference)
//
#include <hip/hip_runtime.h>

#define HW    3136
#define HDIM  56
#define CIN   256
#define CR    64
#define NG    16
#define CG    16
#define KK    49
#define BEPS  1e-5f
#define CHUNKS1 13   // ceil(3136/256)

// K1: t[b, o, pix] = relu( (sum_c x[b,c,pix]*W1[o,c] + b1[o]) * scale + beta - mean*scale )
__global__ __launch_bounds__(256) void k1_conv_bn_relu(
    const float* __restrict__ x, const float* __restrict__ W1,
    const float* __restrict__ b1, const float* __restrict__ gamma,
    const float* __restrict__ beta, const float* __restrict__ mean,
    const float* __restrict__ var, float* __restrict__ t_out)
{
    int bx = blockIdx.x;
    int b = bx / CHUNKS1, chunk = bx % CHUNKS1;
    int pix = chunk * 256 + threadIdx.x;
    if (pix >= HW) return;
    int og = blockIdx.y;            // 0..7, each handles 8 of 64 outputs

    float acc[8];
#pragma unroll
    for (int k = 0; k < 8; k++) acc[k] = 0.f;

    const float* xb = x + (size_t)b * CIN * HW + pix;
    for (int c = 0; c < CIN; c++) {
        float xv = xb[(size_t)c * HW];
#pragma unroll
        for (int k = 0; k < 8; k++)
            acc[k] += xv * W1[(og * 8 + k) * CIN + c];   // uniform -> s_load
    }

#pragma unroll
    for (int k = 0; k < 8; k++) {
        int o = og * 8 + k;
        float s = gamma[o] * rsqrtf(var[o] + BEPS);
        float v = acc[k] * s + (b1[o] * s + beta[o] - mean[o] * s);
        t_out[((size_t)b * CR + o) * HW + pix] = fmaxf(v, 0.f);
    }
}

// K23: per 16-pixel chunk: compute per-pixel kernels w[g,49] from t, then involution.
// Block: 256 threads = 16 pixels (low 4 bits) x 16 groups.
__global__ __launch_bounds__(256) void k23_kgen_involution(
    const float* __restrict__ x, const float* __restrict__ t_in,
    const float* __restrict__ W2, const float* __restrict__ b2,
    float* __restrict__ out)
{
    __shared__ float lds_t[16 * 68];   // [pixel_lane][c], stride 68 (16B-aligned, conflict-safe)

    int bx = blockIdx.x;
    int b = bx / (HW / 16), chunk = bx % (HW / 16);
    int pix0 = chunk * 16;
    int tid = threadIdx.x;
    int pl = tid & 15;     // pixel lane
    int g  = tid >> 4;     // group

    // stage t tile: 64 c x 16 pixels
#pragma unroll
    for (int i = 0; i < 4; i++) {
        int flat = tid + i * 256;
        int c = flat >> 4, p = flat & 15;
        lds_t[p * 68 + c] = t_in[((size_t)b * CR + c) * HW + pix0 + p];
    }
    __syncthreads();

    // kernel generation: wr[tap] = b2 + sum_c t[c] * W2[g*49+tap, c]
    float wr[KK];
#pragma unroll
    for (int tap = 0; tap < KK; tap++) wr[tap] = b2[g * KK + tap];

    const float* w2g = W2 + (size_t)g * KK * CR;
    for (int c4 = 0; c4 < 16; c4++) {
        float4 t4 = *(const float4*)&lds_t[pl * 68 + c4 * 4];
#pragma unroll
        for (int tap = 0; tap < KK; tap++) {
            float4 w4 = *(const float4*)&w2g[tap * CR + c4 * 4];
            wr[tap] += t4.x * w4.x + t4.y * w4.y + t4.z * w4.z + t4.w * w4.w;
        }
    }

    // involution: out[b, g*16+cg, h, w] = sum_taps x[b, g*16+cg, h+di-3, w+dj-3] * wr[di*7+dj]
    int pix = pix0 + pl;
    int h = pix / HDIM, w = pix % HDIM;
    const float* xc = x + ((size_t)b * CIN + g * CG) * HW;
    float* oc = out + ((size_t)b * CIN + g * CG) * HW + pix;

    for (int cg = 0; cg < CG; cg++) {
        const float* xch = xc + (size_t)cg * HW;
        float acc = 0.f;
#pragma unroll
        for (int di = 0; di < 7; di++) {
            int hy = h + di - 3;
            if (hy < 0 || hy >= HDIM) continue;
#pragma unroll
            for (int dj = 0; dj < 7; dj++) {
                int wx = w + dj - 3;
                if (wx < 0 || wx >= HDIM) continue;
                acc += xch[hy * HDIM + wx] * wr[di * 7 + dj];
            }
        }
        oc[(size_t)cg * HW] = acc;
    }
}

extern "C" void kernel_launch(void* const* d_in, const int* in_sizes, int n_in,
                              void* d_out, int out_size, void* d_ws, size_t ws_size,
                              hipStream_t stream) {
    const float* x     = (const float*)d_in[0];
    const float* W1    = (const float*)d_in[1];
    const float* b1    = (const float*)d_in[2];
    const float* gamma = (const float*)d_in[3];
    const float* beta  = (const float*)d_in[4];
    const float* mean  = (const float*)d_in[5];
    const float* var   = (const float*)d_in[6];
    const float* W2    = (const float*)d_in[7];
    const float* b2    = (const float*)d_in[8];
    float* out = (float*)d_out;

    float* t_buf = (float*)d_ws;   // 4*64*3136 floats = 3.21 MB

    dim3 grid1(4 * CHUNKS1, 8);
    k1_conv_bn_relu<<<grid1, 256, 0, stream>>>(x, W1, b1, gamma, beta, mean, var, t_buf);

    dim3 grid23(4 * (HW / 16));
    k23_kgen_involution<<<grid23, 256, 0, stream>>>(x, t_buf, W2, b2, out);
}

// Round 2
// 304.147 us; speedup vs baseline: 1.1189x; 1.1189x over previous
//
#include <hip/hip_runtime.h>

#define HW      3136
#define HDIM    56
#define CIN     256
#define CR      64
#define NG      16
#define CG      16
#define KK      49
#define BEPS    1e-5f
#define NCHUNK  196      // HW / 16 pixel-chunks per batch image
#define TSTRIDE 68       // t_lds row stride (floats): 64 + 4 pad, 16B-aligned
#define WSTRIDE 788      // w_lds row stride (floats): 784 + 4 pad

// k0: fold BN into conv1 weights and transpose for coalesced access.
// W1f[c*64+o] = W1[o*256+c] * scale[o];  b1f[o] = b1[o]*s + beta[o] - mean[o]*s
__global__ __launch_bounds__(256) void k0_fold(
    const float* __restrict__ W1, const float* __restrict__ b1,
    const float* __restrict__ gamma, const float* __restrict__ beta,
    const float* __restrict__ mean, const float* __restrict__ var,
    float* __restrict__ W1f, float* __restrict__ b1f)
{
    int idx = blockIdx.x * 256 + threadIdx.x;      // 0..16383
    int o = idx & 63, c = idx >> 6;
    float s = gamma[o] * rsqrtf(var[o] + BEPS);
    W1f[c * CR + o] = W1[o * CIN + c] * s;
    if (idx < CR) b1f[idx] = b1[idx] * s + beta[idx] - mean[idx] * s;
}

// Fused: conv1+BN+ReLU (phase 0) -> kernel-gen GEMM (phase A) -> involution (phase B).
// Block = 256 threads = 16 pixels (p = tid&15) x 16 slices/groups (s = tid>>4).
// All per-thread arrays <= 16 elements, statically indexed -> registers, no scratch.
__global__ __launch_bounds__(256, 2) void k_fused(
    const float* __restrict__ x, const float* __restrict__ W1f,
    const float* __restrict__ b1f, const float* __restrict__ W2,
    const float* __restrict__ b2, float* __restrict__ out)
{
    __shared__ float t_lds[16 * TSTRIDE];   // 4.35 KB: t[pixel][c]
    __shared__ float w_lds[16 * WSTRIDE];   // 50.4 KB: w[pixel][784 outputs]

    int bx = blockIdx.x;
    int b = bx / NCHUNK, chunk = bx % NCHUNK;
    int pix0 = chunk * 16;
    int tid = threadIdx.x;
    int p = tid & 15;        // pixel lane
    int s = tid >> 4;        // slice (phase 0) / group (phases A,B)

    // ---------- phase 0: t[p][4s..4s+3] = relu(x . W1f + b1f) ----------
    {
        const float* xb = x + (size_t)b * CIN * HW + pix0 + p;
        float4 a = *(const float4*)&b1f[s * 4];
#pragma unroll 8
        for (int c = 0; c < CIN; c++) {
            float xv = xb[(size_t)c * HW];
            float4 w4 = *(const float4*)&W1f[c * CR + s * 4];
            a.x += xv * w4.x; a.y += xv * w4.y; a.z += xv * w4.z; a.w += xv * w4.w;
        }
        a.x = fmaxf(a.x, 0.f); a.y = fmaxf(a.y, 0.f);
        a.z = fmaxf(a.z, 0.f); a.w = fmaxf(a.w, 0.f);
        *(float4*)&t_lds[p * TSTRIDE + s * 4] = a;
    }
    __syncthreads();

    // ---------- phase A: w[p][g*49+tap] = b2 + t[p][:] . W2[g*49+tap][:] ----------
    {
        int g = s;
        const float* w2g = W2 + (size_t)g * KK * CR;
        const float* b2g = b2 + g * KK;
        for (int cc = 0; cc < 7; cc++) {          // 7 chunks x 7 outputs
            float acc7[7];
#pragma unroll
            for (int i = 0; i < 7; i++) acc7[i] = b2g[cc * 7 + i];
            for (int c4 = 0; c4 < 16; c4++) {
                float4 t4 = *(const float4*)&t_lds[p * TSTRIDE + c4 * 4];
#pragma unroll
                for (int i = 0; i < 7; i++) {
                    float4 w4 = *(const float4*)&w2g[(cc * 7 + i) * CR + c4 * 4];
                    acc7[i] += t4.x * w4.x + t4.y * w4.y + t4.z * w4.z + t4.w * w4.w;
                }
            }
#pragma unroll
            for (int i = 0; i < 7; i++)
                w_lds[p * WSTRIDE + g * KK + cc * 7 + i] = acc7[i];
        }
    }
    __syncthreads();

    // ---------- phase B: involution, tap-outer, acc over 16 channels ----------
    {
        int g = s;
        int pix = pix0 + p;
        int h = pix / HDIM, w = pix % HDIM;
        const float* xg = x + ((size_t)b * CIN + g * CG) * HW;
        float acc[16];
#pragma unroll
        for (int cg = 0; cg < 16; cg++) acc[cg] = 0.f;

        for (int di = 0; di < 7; di++) {
            int hy = h + di - 3;
            int hyc = min(max(hy, 0), HDIM - 1);
            bool rowok = (hy >= 0) & (hy < HDIM);
            for (int dj = 0; dj < 7; dj++) {
                int wx = w + dj - 3;
                int wxc = min(max(wx, 0), HDIM - 1);
                bool ok = rowok & (wx >= 0) & (wx < HDIM);
                float wt = w_lds[p * WSTRIDE + g * KK + di * 7 + dj];
                wt = ok ? wt : 0.f;
                const float* xp = xg + hyc * HDIM + wxc;
#pragma unroll
                for (int cg = 0; cg < 16; cg++)
                    acc[cg] += xp[(size_t)cg * HW] * wt;
            }
        }
        float* op = out + ((size_t)b * CIN + g * CG) * HW + pix;
#pragma unroll
        for (int cg = 0; cg < 16; cg++) op[(size_t)cg * HW] = acc[cg];
    }
}

extern "C" void kernel_launch(void* const* d_in, const int* in_sizes, int n_in,
                              void* d_out, int out_size, void* d_ws, size_t ws_size,
                              hipStream_t stream) {
    const float* x     = (const float*)d_in[0];
    const float* W1    = (const float*)d_in[1];
    const float* b1    = (const float*)d_in[2];
    const float* gamma = (const float*)d_in[3];
    const float* beta  = (const float*)d_in[4];
    const float* mean  = (const float*)d_in[5];
    const float* var   = (const float*)d_in[6];
    const float* W2    = (const float*)d_in[7];
    const float* b2    = (const float*)d_in[8];
    float* out = (float*)d_out;

    float* W1f = (float*)d_ws;            // 16384 floats
    float* b1f = W1f + CIN * CR;          // 64 floats (ws >= 66 KB, had 3.2 MB before)

    k0_fold<<<CIN * CR / 256, 256, 0, stream>>>(W1, b1, gamma, beta, mean, var, W1f, b1f);

    k_fused<<<4 * NCHUNK, 256, 0, stream>>>(x, W1f, b1f, W2, b2, out);
}

// Round 3
// 209.683 us; speedup vs baseline: 1.6229x; 1.4505x over previous
//
#include <hip/hip_runtime.h>

#define HW    3136
#define HDIM  56
#define CIN   256
#define CR    64
#define NG    16
#define CG    16
#define KK    49
#define BEPS  1e-5f
#define RB    4            // rows per band in k2
#define NBAND 14           // 56 / RB
#define PXB   (RB * HDIM)  // 224 pixels per band
#define WSTR  228          // w_lds row stride (224 px + 4 pad, 16B-aligned)

// k0: fold BN into conv1 weights, transpose to [c][o] for k1's uniform loads.
__global__ __launch_bounds__(256) void k0_fold(
    const float* __restrict__ W1, const float* __restrict__ b1,
    const float* __restrict__ gamma, const float* __restrict__ beta,
    const float* __restrict__ mean, const float* __restrict__ var,
    float* __restrict__ W1f, float* __restrict__ b1f)
{
    int idx = blockIdx.x * 256 + threadIdx.x;      // 0..16383
    int o = idx & 63, c = idx >> 6;
    float s = gamma[o] * rsqrtf(var[o] + BEPS);
    W1f[c * CR + o] = W1[o * CIN + c] * s;
    if (idx < CR) b1f[idx] = b1[idx] * s + beta[idx] - mean[idx] * s;
}

// k1: t[b][px][64] = relu(x . W1f + b1f). Block=128 px-lanes; 8 channels from
// blockIdx.y (wave-uniform -> W1f via s_load).
__global__ __launch_bounds__(128) void k1_conv(
    const float* __restrict__ x, const float* __restrict__ W1f,
    const float* __restrict__ b1f, float* __restrict__ t_out)
{
    int px = blockIdx.x * 128 + threadIdx.x;
    if (px >= HW) return;
    int grp = blockIdx.y;          // 8 channels: grp*8 .. grp*8+7
    int b = blockIdx.z;

    float4 a0 = *(const float4*)&b1f[grp * 8];
    float4 a1 = *(const float4*)&b1f[grp * 8 + 4];
    const float* xb = x + (size_t)b * CIN * HW + px;
#pragma unroll 8
    for (int c = 0; c < CIN; c++) {
        float xv = xb[(size_t)c * HW];
        float4 w0 = *(const float4*)&W1f[c * CR + grp * 8];
        float4 w1 = *(const float4*)&W1f[c * CR + grp * 8 + 4];
        a0.x += xv * w0.x; a0.y += xv * w0.y; a0.z += xv * w0.z; a0.w += xv * w0.w;
        a1.x += xv * w1.x; a1.y += xv * w1.y; a1.z += xv * w1.z; a1.w += xv * w1.w;
    }
    a0.x = fmaxf(a0.x, 0.f); a0.y = fmaxf(a0.y, 0.f);
    a0.z = fmaxf(a0.z, 0.f); a0.w = fmaxf(a0.w, 0.f);
    a1.x = fmaxf(a1.x, 0.f); a1.y = fmaxf(a1.y, 0.f);
    a1.z = fmaxf(a1.z, 0.f); a1.w = fmaxf(a1.w, 0.f);
    float* tp = t_out + ((size_t)b * HW + px) * CR + grp * 8;
    *(float4*)&tp[0] = a0;
    *(float4*)&tp[4] = a1;
}

// k2: fused kernel-gen + involution for one (b, g, 4-row band).
// Phase A: thread=pixel, t in regs, W2 via scalar loads -> w_lds[tap][px].
// Phase B: thread=(col-quad, row, 4-cg group), x streamed from global.
__global__ __launch_bounds__(256, 2) void k2_kgen_inv(
    const float* __restrict__ x, const float* __restrict__ t_in,
    const float* __restrict__ W2, const float* __restrict__ b2,
    float* __restrict__ out)
{
    __shared__ float w_lds[KK * WSTR];   // 44.7 KB

    const int tid = threadIdx.x;
    const int band = blockIdx.x, g = blockIdx.y, b = blockIdx.z;
    const int h0 = band * RB;

    // ---------- phase A: w[tap][px] for 224 pixels ----------
    if (tid < PXB) {
        const int px = tid;   // band-local; global pixel = h0*56 + px
        const float* tp = t_in + ((size_t)b * HW + h0 * HDIM + px) * CR;
        float4 tq[16];
#pragma unroll
        for (int i = 0; i < 16; i++) tq[i] = *(const float4*)&tp[i * 4];

        const float* w2g = W2 + (size_t)g * KK * CR;
        const float* b2g = b2 + g * KK;
#pragma unroll 1
        for (int cc = 0; cc < 7; cc++) {      // 7 chunks of 7 taps
            float a[7];
#pragma unroll
            for (int i = 0; i < 7; i++) a[i] = b2g[cc * 7 + i];
#pragma unroll
            for (int c4 = 0; c4 < 16; c4++) {
                float4 t4 = tq[c4];
#pragma unroll
                for (int i = 0; i < 7; i++) {
                    float4 w4 = *(const float4*)&w2g[(cc * 7 + i) * CR + c4 * 4];
                    a[i] += t4.x * w4.x + t4.y * w4.y + t4.z * w4.z + t4.w * w4.w;
                }
            }
#pragma unroll
            for (int i = 0; i < 7; i++)
                w_lds[(cc * 7 + i) * WSTR + px] = a[i];
        }
    }
    __syncthreads();

    // ---------- phase B: involution ----------
    if (tid < 224) {
        const int quad = tid % 14;          // output col quad: cols quad*4..+3
        const int tmp  = tid / 14;
        const int row  = tmp & 3;           // band-local row
        const int cgp  = tmp >> 2;          // 0..3 -> channels cgp*4..+3
        const int colb = quad * 4;
        const int cb   = colb - 4;          // 12-col window base (use m=1..10)
        const int h    = h0 + row;
        const int px0  = row * HDIM + colb;
        const bool okL = quad > 0, okR = quad < 13;

        float acc[4][4];
#pragma unroll
        for (int i = 0; i < 4; i++)
#pragma unroll
            for (int k = 0; k < 4; k++) acc[i][k] = 0.f;

        const float* xg = x + ((size_t)b * CIN + g * CG + cgp * 4) * HW;
        const float4 z4 = make_float4(0.f, 0.f, 0.f, 0.f);

#pragma unroll 1
        for (int di = 0; di < 7; di++) {
            int hy = h + di - 3;
            bool rok = (hy >= 0) & (hy < HDIM);
            int hyc = min(max(hy, 0), HDIM - 1);
            float4 wv[7];
#pragma unroll
            for (int dj = 0; dj < 7; dj++)
                wv[dj] = *(const float4*)&w_lds[(di * 7 + dj) * WSTR + px0];

#pragma unroll 1
            for (int cgi = 0; cgi < 4; cgi++) {
                const float* xrow = xg + (size_t)cgi * HW + hyc * HDIM;
                float4 A  = (rok && okL) ? *(const float4*)&xrow[cb]     : z4;
                float4 Bv = rok          ? *(const float4*)&xrow[cb + 4] : z4;
                float4 Cv = (rok && okR) ? *(const float4*)&xrow[cb + 8] : z4;
                float win[12] = {A.x, A.y, A.z, A.w, Bv.x, Bv.y, Bv.z, Bv.w,
                                 Cv.x, Cv.y, Cv.z, Cv.w};
#pragma unroll
                for (int dj = 0; dj < 7; dj++) {
                    const float* wp = (const float*)&wv[dj];
#pragma unroll
                    for (int k = 0; k < 4; k++)
                        acc[cgi][k] += win[k + dj + 1] * wp[k];
                }
            }
        }

        float* op = out + ((size_t)b * CIN + g * CG + cgp * 4) * HW + h * HDIM + colb;
#pragma unroll
        for (int cgi = 0; cgi < 4; cgi++)
            *(float4*)&op[(size_t)cgi * HW] =
                make_float4(acc[cgi][0], acc[cgi][1], acc[cgi][2], acc[cgi][3]);
    }
}

extern "C" void kernel_launch(void* const* d_in, const int* in_sizes, int n_in,
                              void* d_out, int out_size, void* d_ws, size_t ws_size,
                              hipStream_t stream) {
    const float* x     = (const float*)d_in[0];
    const float* W1    = (const float*)d_in[1];
    const float* b1    = (const float*)d_in[2];
    const float* gamma = (const float*)d_in[3];
    const float* beta  = (const float*)d_in[4];
    const float* mean  = (const float*)d_in[5];
    const float* var   = (const float*)d_in[6];
    const float* W2    = (const float*)d_in[7];
    const float* b2    = (const float*)d_in[8];
    float* out = (float*)d_out;

    float* t_buf = (float*)d_ws;               // 4*3136*64 = 802816 floats
    float* W1f   = t_buf + 4 * HW * CR;        // 16384 floats
    float* b1f   = W1f + CIN * CR;             // 64 floats   (total 3.28 MB)

    k0_fold<<<CIN * CR / 256, 256, 0, stream>>>(W1, b1, gamma, beta, mean, var, W1f, b1f);

    dim3 g1((HW + 127) / 128, 8, 4);
    k1_conv<<<g1, 128, 0, stream>>>(x, W1f, b1f, t_buf);

    dim3 g2(NBAND, NG, 4);
    k2_kgen_inv<<<g2, 256, 0, stream>>>(x, t_buf, W2, b2, out);
}